// Round 9
// baseline (368.368 us; speedup 1.0000x reference)
//
#include <hip/hip_runtime.h>

#define NC 50000
#define NG 3000
#define D  64

#define NB_CG 750   // gene bins of 4  (SHIFT 2)
#define NB_GC 782   // cell bins of 64 (SHIFT 6), 782*64 = 50048
#define PBITS 18
#define TILE  4096
#define NHIST 576
#define NPREP 128
#define CAPV  6144

__device__ inline unsigned short f2bf(float x) {
    unsigned u = __float_as_uint(x);
    unsigned r = u + 0x7FFFu + ((u >> 16) & 1u);
    return (unsigned short)(r >> 16);
}

// 8-lane row loader: lane l8 holds 8 elements of row s.
template <bool BF16>
__device__ inline void row8(const void* feat, int s, int l8, float f[8]) {
    if (BF16) {
        const uint4 q = *((const uint4*)((const unsigned short*)feat + (size_t)s * D) + l8);
        f[0] = __uint_as_float(q.x << 16); f[1] = __uint_as_float(q.x & 0xFFFF0000u);
        f[2] = __uint_as_float(q.y << 16); f[3] = __uint_as_float(q.y & 0xFFFF0000u);
        f[4] = __uint_as_float(q.z << 16); f[5] = __uint_as_float(q.z & 0xFFFF0000u);
        f[6] = __uint_as_float(q.w << 16); f[7] = __uint_as_float(q.w & 0xFFFF0000u);
    } else {
        const float4* row = (const float4*)((const float*)feat + (size_t)s * D);
        const float4 a = row[l8];
        const float4 b = row[l8 + 8];
        f[0] = a.x; f[1] = a.y; f[2] = a.z; f[3] = a.w;
        f[4] = b.x; f[5] = b.y; f[6] = b.z; f[7] = b.w;
    }
}

// ======================= stage1: hist (cg|gc|gg) + prep + last-block scan =======================

__global__ __launch_bounds__(256) void stage1_kernel(
    const int* __restrict__ dst_cg, int e_cg, int* __restrict__ cnt_cg,
    const int* __restrict__ dst_gc, int e_gc, int* __restrict__ cnt_gc,
    const int* __restrict__ dst_gg, int e_gg, int* __restrict__ cnt_gg,
    int* __restrict__ off_cg, int* __restrict__ cur_cg,
    int* __restrict__ off_gc, int* __restrict__ cur_gc,
    int* __restrict__ off_gg, int* __restrict__ cur_gg,
    int* __restrict__ done,
    const float* __restrict__ cj_cell, const float* __restrict__ mask_exp,
    const float* __restrict__ cj_gene, const float* __restrict__ mask_rev,
    const float* __restrict__ cjj_gene, const float* __restrict__ mask_gg,
    float* __restrict__ w_cell, float* __restrict__ w_rev, float* __restrict__ w_gg,
    const float* __restrict__ c_feat, const float* __restrict__ g_feat,
    unsigned short* __restrict__ cf16, unsigned short* __restrict__ gf16, int do_cvt)
{
    const int tid = threadIdx.x;

    if (blockIdx.x >= NHIST) {              // ---- prep blocks ----
        const int pb = blockIdx.x - NHIST;
        const long long stride = (long long)NPREP * 256;
        for (long long i = (long long)pb * 256 + tid; i < NC; i += stride)
            w_cell[i] = cj_cell[i] * mask_exp[i];
        for (long long i = (long long)pb * 256 + tid; i < NG; i += stride) {
            w_rev[i] = cj_gene[i] * mask_rev[i];
            w_gg[i]  = cjj_gene[i] * mask_gg[i];
        }
        if (do_cvt) {
            const long long total8 = (long long)(NC + NG) * D / 8;
            for (long long t = (long long)pb * 256 + tid; t < total8; t += stride) {
                const long long base = t * 8;
                const float* sp; unsigned short* dp;
                if (base < (long long)NC * D) { sp = c_feat + base; dp = cf16 + base; }
                else { sp = g_feat + (base - (long long)NC * D); dp = gf16 + (base - (long long)NC * D); }
                const float4 a = ((const float4*)sp)[0];
                const float4 b = ((const float4*)sp)[1];
                ((ushort4*)dp)[0] = make_ushort4(f2bf(a.x), f2bf(a.y), f2bf(a.z), f2bf(a.w));
                ((ushort4*)dp)[1] = make_ushort4(f2bf(b.x), f2bf(b.y), f2bf(b.z), f2bf(b.w));
            }
        }
        return;
    }

    // ---- histogram blocks ----
    __shared__ int h[NG];                   // 12 KB, max of the three bin counts
    const int* dst; int* cnt; int ne, nbins, shift, bid, nblk;
    if (blockIdx.x < 256)      { dst = dst_cg; cnt = cnt_cg; ne = e_cg; nbins = NB_CG; shift = 2; bid = blockIdx.x;       nblk = 256; }
    else if (blockIdx.x < 512) { dst = dst_gc; cnt = cnt_gc; ne = e_gc; nbins = NB_GC; shift = 6; bid = blockIdx.x - 256; nblk = 256; }
    else                       { dst = dst_gg; cnt = cnt_gg; ne = e_gg; nbins = NG;    shift = 0; bid = blockIdx.x - 512; nblk = 64;  }
    for (int i = tid; i < nbins; i += 256) h[i] = 0;
    __syncthreads();
    for (long long e = (long long)bid * 256 + tid; e < ne; e += (long long)nblk * 256) {
        unsigned b = ((unsigned)dst[e]) >> shift;
        if (b < (unsigned)nbins) atomicAdd(&h[b], 1);
    }
    __syncthreads();
    for (int i = tid; i < nbins; i += 256) {
        int v = h[i];
        if (v) atomicAdd(&cnt[i], v);
    }

    // ---- last hist block performs the three scans ----
    __threadfence();
    __shared__ int lastflag;
    if (tid == 0) lastflag = (atomicAdd(done, 1) == NHIST - 1) ? 1 : 0;
    __syncthreads();
    if (!lastflag) return;
    __threadfence();

    __shared__ int s_wtot[4];
    __shared__ int s_woff[4];
    __shared__ int s_tot;
    __shared__ int s_carry;
    const int lane = tid & 63;
    const int wid  = tid >> 6;
    for (int a = 0; a < 3; ++a) {
        const int* c; int* o; int* u; int n; int pad;
        if (a == 0)      { c = cnt_cg; o = off_cg; u = cur_cg; n = NB_CG; pad = 1; }
        else if (a == 1) { c = cnt_gc; o = off_gc; u = cur_gc; n = NB_GC; pad = 1; }
        else             { c = cnt_gg; o = off_gg; u = cur_gg; n = NG;    pad = 0; }
        if (tid == 0) s_carry = 0;
        __syncthreads();
        for (int base = 0; base < n; base += 256) {
            int i = base + tid;
            int v = (i < n) ? c[i] : 0;
            if (pad) v = (v + 15) & ~15;
            int incl = v;
            #pragma unroll
            for (int d = 1; d < 64; d <<= 1) {
                int t = __shfl_up(incl, d);
                if (lane >= d) incl += t;
            }
            if (lane == 63) s_wtot[wid] = incl;
            __syncthreads();
            if (tid < 4) {
                int t = s_wtot[tid];
                int s = t;
                #pragma unroll
                for (int d = 1; d < 4; d <<= 1) {
                    int x = __shfl_up(s, d);
                    if (tid >= d) s += x;
                }
                s_woff[tid] = s - t;
                if (tid == 3) s_tot = s;
            }
            __syncthreads();
            int excl = incl - v + s_woff[wid] + s_carry;
            if (i < n) { o[i] = excl; u[i] = excl; }
            __syncthreads();
            if (tid == 0) s_carry += s_tot;
            __syncthreads();
        }
        if (tid == 0) o[n] = s_carry;
        __syncthreads();
    }
}

// ======================= fused partition (cg | gc) + gg fill, one tile per block =======================

__global__ __launch_bounds__(256) void part3_kernel(
    const int* __restrict__ src_cg, const int* __restrict__ dst_cg, int e_cg,
    int* __restrict__ cur_cg, unsigned* __restrict__ ubkt_cg, int cap_cg,
    const int* __restrict__ src_gc, const int* __restrict__ dst_gc, int e_gc,
    int* __restrict__ cur_gc, unsigned* __restrict__ ubkt_gc, int cap_gc,
    const int* __restrict__ src_gg, const int* __restrict__ dst_gg, int e_gg,
    int* __restrict__ cur_gg, int* __restrict__ bkt_gg,
    int nt_cg, int nt_gc)
{
    const int tid = threadIdx.x;
    if (blockIdx.x >= nt_cg + nt_gc) {   // gg fill (64 blocks)
        for (long long e = (long long)(blockIdx.x - nt_cg - nt_gc) * 256 + tid; e < e_gg;
             e += (long long)64 * 256) {
            int pos = atomicAdd(&cur_gg[dst_gg[e]], 1);
            if (pos >= 0 && pos < e_gg) bkt_gg[pos] = src_gg[e];
        }
        return;
    }
    const int* src; const int* dst; int ne; int* ccur; unsigned* bkt; int cap, shift, nbins; long long tbase;
    if (blockIdx.x < nt_cg) { src = src_cg; dst = dst_cg; ne = e_cg; ccur = cur_cg; bkt = ubkt_cg; cap = cap_cg; shift = 2; nbins = NB_CG; tbase = (long long)blockIdx.x * TILE; }
    else                    { src = src_gc; dst = dst_gc; ne = e_gc; ccur = cur_gc; bkt = ubkt_gc; cap = cap_gc; shift = 6; nbins = NB_GC; tbase = (long long)(blockIdx.x - nt_cg) * TILE; }
    if (tbase >= ne) return;

    __shared__ int th[784];
    __shared__ int toff[784];
    __shared__ int tcur[784];
    __shared__ int gb[784];
    __shared__ unsigned staged[TILE];
    const unsigned PMASK = (1u << PBITS) - 1u;
    const unsigned DMASK = (1u << shift) - 1u;

    const int n = (int)((ne - tbase) < TILE ? (ne - tbase) : TILE);
    for (int i = tid; i < nbins; i += 256) { th[i] = 0; tcur[i] = 0; }
    __syncthreads();
    #pragma unroll 4
    for (int k = 0; k < TILE / 256; ++k) {
        int i = k * 256 + tid;
        if (i < n) {
            unsigned b = ((unsigned)dst[tbase + i]) >> shift;
            if (b < (unsigned)nbins) atomicAdd(&th[b], 1);
        }
    }
    __syncthreads();
    if (tid < 64) {
        int carry = 0;
        for (int c = 0; c < nbins; c += 64) {
            int idx = c + tid;
            int v = (idx < nbins) ? th[idx] : 0;
            int incl = v;
            #pragma unroll
            for (int d = 1; d < 64; d <<= 1) {
                int t = __shfl_up(incl, d);
                if (tid >= d) incl += t;
            }
            if (idx < nbins) toff[idx] = incl - v + carry;
            carry += __shfl(incl, 63);
        }
    }
    __syncthreads();
    for (int i = tid; i < nbins; i += 256) {
        int c = th[i];
        if (c) gb[i] = atomicAdd(&ccur[i], c);
    }
    __syncthreads();
    #pragma unroll 4
    for (int k = 0; k < TILE / 256; ++k) {
        int i = k * 256 + tid;
        if (i < n) {
            unsigned d = (unsigned)dst[tbase + i];
            unsigned s = (unsigned)src[tbase + i];
            unsigned b = d >> shift;
            if (b < (unsigned)nbins) {
                int p = toff[b] + atomicAdd(&tcur[b], 1);
                if (p >= 0 && p < TILE)
                    staged[p] = (b << PBITS) | (s << shift) | (d & DMASK);
            }
        }
    }
    __syncthreads();
    for (int i = tid; i < n; i += 256) {
        unsigned v = staged[i];
        unsigned b = v >> PBITS;
        long long g = (long long)gb[b] + (i - toff[b]);
        if (g >= 0 && g < cap) bkt[g] = v & PMASK;
    }
}

// ======================= fused gather (cg + gg fold | gc), src-tile-sorted =======================

template <bool BF16>
__global__ __launch_bounds__(256) void gather3_kernel(
    const unsigned* __restrict__ ubkt_cg, const int* __restrict__ cntb_cg, const int* __restrict__ offb_cg,
    const unsigned* __restrict__ ubkt_gc, const int* __restrict__ cntb_gc, const int* __restrict__ offb_gc,
    const void* __restrict__ cfeat, const void* __restrict__ gfeat,
    const float* __restrict__ w_cell, const float* __restrict__ w_rev, const float* __restrict__ w_gg,
    const float* __restrict__ ci_gene, const float* __restrict__ cii_gene, const float* __restrict__ ci_cell,
    const int* __restrict__ off_gg, const int* __restrict__ bkt_gg, int e_gg,
    float* __restrict__ g_out, float* __restrict__ c_out)
{
    __shared__ unsigned sorted[CAPV];
    __shared__ int lh[64];
    __shared__ int loff[64];
    __shared__ int lcur[64];

    const bool is_cg = (blockIdx.x < NB_CG);
    const int bin = is_cg ? blockIdx.x : blockIdx.x - NB_CG;
    const int n = (is_cg ? cntb_cg : cntb_gc)[bin];
    const long long base = (is_cg ? offb_cg : offb_gc)[bin];
    const unsigned* bkt = is_cg ? ubkt_cg : ubkt_gc;
    const void* feat = is_cg ? cfeat : gfeat;
    const float* wsrc = is_cg ? w_cell : w_rev;
    const int shift = is_cg ? 2 : 6;
    const int DIVv = is_cg ? 4 : 64;
    const int KPC  = is_cg ? 16 : 1;     // sort keys per cell
    const int tid  = threadIdx.x;
    const int lane = tid & 63;
    const int wid  = tid >> 6;
    const int grp8 = lane >> 3;          // 8 groups of 8 lanes -> 8 edges in flight
    const int l8   = lane & 7;
    const bool fast = (n <= CAPV);

    if (fast) {
        for (int i = tid; i < 64; i += 256) { lh[i] = 0; lcur[i] = 0; }
        __syncthreads();
        for (int i = tid; i < n; i += 256) {
            const unsigned v = bkt[base + i];
            const int k = is_cg ? (int)(((v & 3u) << 4) | (((v >> 2) & 0xFFFFu) >> 12))
                                : (int)(v & 63u);
            atomicAdd(&lh[k], 1);
        }
        __syncthreads();
        if (tid < 64) {
            int v = lh[tid];
            int incl = v;
            #pragma unroll
            for (int d = 1; d < 64; d <<= 1) {
                int t = __shfl_up(incl, d);
                if (tid >= d) incl += t;
            }
            loff[tid] = incl - v;
        }
        __syncthreads();
        for (int i = tid; i < n; i += 256) {
            const unsigned v = bkt[base + i];
            const int k = is_cg ? (int)(((v & 3u) << 4) | (((v >> 2) & 0xFFFFu) >> 12))
                                : (int)(v & 63u);
            int p = loff[k] + atomicAdd(&lcur[k], 1);
            if (p >= 0 && p < CAPV) sorted[p] = v;
        }
        __syncthreads();
    }

    for (int cell = wid; cell < DIVv; cell += 4) {
        const int r = (bin << shift) + cell;
        if (r >= (is_cg ? NG : NC)) continue;

        float fA[8] = {0.f, 0.f, 0.f, 0.f, 0.f, 0.f, 0.f, 0.f};
        if (fast) {
            const int k0 = cell * KPC, k1 = k0 + KPC - 1;
            const int lo = loff[k0], hi = loff[k1] + lh[k1];
            for (int jj = lo; jj < hi; jj += 8) {
                const int j = jj + grp8;
                const bool valid = (j < hi);
                const unsigned v = valid ? sorted[j] : 0u;
                const int s = (v >> shift) & 0xFFFF;
                const float w = valid ? wsrc[s] : 0.0f;
                float f[8]; row8<BF16>(feat, s, l8, f);
                #pragma unroll
                for (int q = 0; q < 8; ++q) fA[q] += w * f[q];
            }
        } else {
            for (int jj = 0; jj < n; jj += 8) {
                const int j = jj + grp8;
                const bool valid = (j < n);
                const unsigned v = valid ? bkt[base + j] : 0u;
                const bool ok = valid && ((int)(v & (unsigned)(DIVv - 1)) == cell);
                const int s = (v >> shift) & 0xFFFF;
                const float w = ok ? wsrc[s] : 0.0f;
                float f[8]; row8<BF16>(feat, s, l8, f);
                #pragma unroll
                for (int q = 0; q < 8; ++q) fA[q] += w * f[q];
            }
        }

        float fB[8] = {0.f, 0.f, 0.f, 0.f, 0.f, 0.f, 0.f, 0.f};
        if (is_cg) {
            int lo2 = off_gg[r], hi2 = off_gg[r + 1];
            lo2 = lo2 < 0 ? 0 : (lo2 > e_gg ? e_gg : lo2);
            hi2 = hi2 < 0 ? 0 : (hi2 > e_gg ? e_gg : hi2);
            for (int jj = lo2; jj < hi2; jj += 8) {
                const int j = jj + grp8;
                const bool valid = (j < hi2);
                const int s = valid ? bkt_gg[j] : 0;
                const float w = valid ? w_gg[s] : 0.0f;
                float f[8]; row8<BF16>(gfeat, s, l8, f);
                #pragma unroll
                for (int q = 0; q < 8; ++q) fB[q] += w * f[q];
            }
        }

        #pragma unroll
        for (int q = 0; q < 8; ++q) {
            #pragma unroll
            for (int off = 8; off < 64; off <<= 1) fA[q] += __shfl_xor(fA[q], off);
        }
        if (is_cg) {
            #pragma unroll
            for (int q = 0; q < 8; ++q) {
                #pragma unroll
                for (int off = 8; off < 64; off <<= 1) fB[q] += __shfl_xor(fB[q], off);
            }
        }

        if (grp8 == 0) {
            float o[8];
            float* outp;
            if (is_cg) {
                const float sa = 0.5f * ci_gene[r];
                const float sb = 0.5f * cii_gene[r];
                outp = g_out + (size_t)r * D;
                #pragma unroll
                for (int q = 0; q < 8; ++q) o[q] = sa * fA[q] + sb * fB[q];
            } else {
                const float sc = ci_cell[r];
                outp = c_out + (size_t)r * D;
                #pragma unroll
                for (int q = 0; q < 8; ++q) o[q] = sc * fA[q];
            }
            if (BF16) {
                *(float4*)(outp + 8 * l8)     = make_float4(o[0], o[1], o[2], o[3]);
                *(float4*)(outp + 8 * l8 + 4) = make_float4(o[4], o[5], o[6], o[7]);
            } else {
                *(float4*)(outp + 4 * l8)      = make_float4(o[0], o[1], o[2], o[3]);
                *(float4*)(outp + 32 + 4 * l8) = make_float4(o[4], o[5], o[6], o[7]);
            }
        }
    }
}

// ======================= fallback (atomic scatter) =======================

__global__ __launch_bounds__(256) void edge_scatter_kernel(
    const float* __restrict__ feat, const float* __restrict__ cj,
    const float* __restrict__ mask, const float* __restrict__ ci,
    const int* __restrict__ src, const int* __restrict__ dst,
    float* __restrict__ out, int nedges, float alpha)
{
    const int lane16 = threadIdx.x & 15;
    const int eloc   = threadIdx.x >> 4;
    const long long e = (long long)blockIdx.x * 16 + eloc;
    if (e >= nedges) return;
    const int s = src[e];
    const int t = dst[e];
    const float w = cj[s] * mask[s] * ci[t] * alpha;
    const float4 v = *(const float4*)(feat + (size_t)s * D + lane16 * 4);
    float* o = out + (size_t)t * D + lane16 * 4;
#if defined(__HIP_DEVICE_COMPILE__)
    unsafeAtomicAdd(o + 0, w * v.x);
    unsafeAtomicAdd(o + 1, w * v.y);
    unsafeAtomicAdd(o + 2, w * v.z);
    unsafeAtomicAdd(o + 3, w * v.w);
#endif
}

// ======================= launch =======================

extern "C" void kernel_launch(void* const* d_in, const int* in_sizes, int n_in,
                              void* d_out, int out_size, void* d_ws, size_t ws_size,
                              hipStream_t stream)
{
    const float* c_feat   = (const float*)d_in[0];
    const float* g_feat   = (const float*)d_in[1];
    const float* cj_cell  = (const float*)d_in[2];
    const float* ci_cell  = (const float*)d_in[3];
    const float* cj_gene  = (const float*)d_in[4];
    const float* ci_gene  = (const float*)d_in[5];
    const float* cjj_gene = (const float*)d_in[6];
    const float* cii_gene = (const float*)d_in[7];
    const float* mask_exp = (const float*)d_in[8];
    const float* mask_rev = (const float*)d_in[9];
    const float* mask_gg  = (const float*)d_in[10];
    const int*   src_cg   = (const int*)d_in[11];
    const int*   dst_cg   = (const int*)d_in[12];
    const int*   src_gc   = (const int*)d_in[13];
    const int*   dst_gc   = (const int*)d_in[14];
    const int*   src_gg   = (const int*)d_in[15];
    const int*   dst_gg   = (const int*)d_in[16];

    const int e_cg = in_sizes[11];
    const int e_gc = in_sizes[13];
    const int e_gg = in_sizes[15];

    float* c_out = (float*)d_out;                   // [NC, D]
    float* g_out = (float*)d_out + (size_t)NC * D;  // [NG, D]

    const int cap_cg = e_cg + 16 * NB_CG;
    const int cap_gc = e_gc + 16 * NB_GC;
    const int nt_cg = (e_cg + TILE - 1) / TILE;
    const int nt_gc = (e_gc + TILE - 1) / TILE;

    // ---- workspace layout (int units) ----
    int* ws = (int*)d_ws;
    size_t p = 0;
    int* cntb_cg = ws + p; p += NB_CG;
    int* cntb_gc = ws + p; p += NB_GC;
    int* cnt_gg  = ws + p; p += NG;
    int* done    = ws + p; p += 1;         // counts+done contiguous -> one memset
    int* offb_cg = ws + p; p += NB_CG + 1;
    int* offb_gc = ws + p; p += NB_GC + 1;
    int* off_gg  = ws + p; p += NG + 1;
    int* curb_cg = ws + p; p += NB_CG;
    int* curb_gc = ws + p; p += NB_GC;
    int* cur_gg  = ws + p; p += NG;
    float* w_cell = (float*)(ws + p); p += NC;
    float* w_rev  = (float*)(ws + p); p += NG;
    float* w_gg   = (float*)(ws + p); p += NG;
    unsigned* ubkt_cg = (unsigned*)(ws + p); p += cap_cg;
    unsigned* ubkt_gc = (unsigned*)(ws + p); p += cap_gc;
    int* bkt_gg = ws + p; p += e_gg;
    const size_t need_base = p * sizeof(int);
    unsigned short* cf16 = (unsigned short*)(ws + p); p += (size_t)NC * D / 2;
    unsigned short* gf16 = (unsigned short*)(ws + p); p += (size_t)NG * D / 2;
    const size_t need_full = p * sizeof(int);

    if (need_base > ws_size) {
        hipMemsetAsync(d_out, 0, (size_t)out_size * sizeof(float), stream);
        edge_scatter_kernel<<<(e_cg + 15) / 16, 256, 0, stream>>>(
            c_feat, cj_cell, mask_exp, ci_gene, src_cg, dst_cg, g_out, e_cg, 0.5f);
        edge_scatter_kernel<<<(e_gc + 15) / 16, 256, 0, stream>>>(
            g_feat, cj_gene, mask_rev, ci_cell, src_gc, dst_gc, c_out, e_gc, 1.0f);
        edge_scatter_kernel<<<(e_gg + 15) / 16, 256, 0, stream>>>(
            g_feat, cjj_gene, mask_gg, cii_gene, src_gg, dst_gg, g_out, e_gg, 0.5f);
        return;
    }
    const int use_bf16 = (need_full <= ws_size) ? 1 : 0;

    hipMemsetAsync(cntb_cg, 0, (size_t)(NB_CG + NB_GC + NG + 1) * sizeof(int), stream);

    stage1_kernel<<<NHIST + NPREP, 256, 0, stream>>>(
        dst_cg, e_cg, cntb_cg, dst_gc, e_gc, cntb_gc, dst_gg, e_gg, cnt_gg,
        offb_cg, curb_cg, offb_gc, curb_gc, off_gg, cur_gg, done,
        cj_cell, mask_exp, cj_gene, mask_rev, cjj_gene, mask_gg,
        w_cell, w_rev, w_gg, c_feat, g_feat, cf16, gf16, use_bf16);

    part3_kernel<<<nt_cg + nt_gc + 64, 256, 0, stream>>>(
        src_cg, dst_cg, e_cg, curb_cg, ubkt_cg, cap_cg,
        src_gc, dst_gc, e_gc, curb_gc, ubkt_gc, cap_gc,
        src_gg, dst_gg, e_gg, cur_gg, bkt_gg, nt_cg, nt_gc);

    if (use_bf16) {
        gather3_kernel<true><<<NB_CG + NB_GC, 256, 0, stream>>>(
            ubkt_cg, cntb_cg, offb_cg, ubkt_gc, cntb_gc, offb_gc,
            (const void*)cf16, (const void*)gf16,
            w_cell, w_rev, w_gg, ci_gene, cii_gene, ci_cell,
            off_gg, bkt_gg, e_gg, g_out, c_out);
    } else {
        gather3_kernel<false><<<NB_CG + NB_GC, 256, 0, stream>>>(
            ubkt_cg, cntb_cg, offb_cg, ubkt_gc, cntb_gc, offb_gc,
            (const void*)c_feat, (const void*)g_feat,
            w_cell, w_rev, w_gg, ci_gene, cii_gene, ci_cell,
            off_gg, bkt_gg, e_gg, g_out, c_out);
    }
}

// Round 10
// 328.573 us; speedup vs baseline: 1.1211x; 1.1211x over previous
//
#include <hip/hip_runtime.h>

#define NC 50000
#define NG 3000
#define D  64

#define NB_CG 750   // gene bins of 4  (SHIFT 2)
#define NB_GC 782   // cell bins of 64 (SHIFT 6), 782*64 = 50048
#define PBITS 18
#define TILE  8192
#define NPREP 128
#define CAPV  6144
#define NSCAN2 7    // 3 blocks (cg bins) + 4 blocks (gc bins)

__device__ inline unsigned short f2bf(float x) {
    unsigned u = __float_as_uint(x);
    unsigned r = u + 0x7FFFu + ((u >> 16) & 1u);
    return (unsigned short)(r >> 16);
}

// 8-lane row loader: lane l8 holds 8 elements of row s.
template <bool BF16>
__device__ inline void row8(const void* feat, int s, int l8, float f[8]) {
    if (BF16) {
        const uint4 q = *((const uint4*)((const unsigned short*)feat + (size_t)s * D) + l8);
        f[0] = __uint_as_float(q.x << 16); f[1] = __uint_as_float(q.x & 0xFFFF0000u);
        f[2] = __uint_as_float(q.y << 16); f[3] = __uint_as_float(q.y & 0xFFFF0000u);
        f[4] = __uint_as_float(q.z << 16); f[5] = __uint_as_float(q.z & 0xFFFF0000u);
        f[6] = __uint_as_float(q.w << 16); f[7] = __uint_as_float(q.w & 0xFFFF0000u);
    } else {
        const float4* row = (const float4*)((const float*)feat + (size_t)s * D);
        const float4 a = row[l8];
        const float4 b = row[l8 + 8];
        f[0] = a.x; f[1] = a.y; f[2] = a.z; f[3] = a.w;
        f[4] = b.x; f[5] = b.y; f[6] = b.z; f[7] = b.w;
    }
}

// 256-thread chunked exclusive scan: c[0..n) -> o[0..n], optional cursor copy.
__device__ __forceinline__ void block_scan256(const int* c, int* o, int* u, int n, int pad)
{
    __shared__ int s_wtot[4];
    __shared__ int s_woff[4];
    __shared__ int s_tot;
    __shared__ int s_carry;
    const int tid  = threadIdx.x;
    const int lane = tid & 63;
    const int wid  = tid >> 6;
    if (tid == 0) s_carry = 0;
    __syncthreads();
    for (int base = 0; base < n; base += 256) {
        int i = base + tid;
        int v = (i < n) ? c[i] : 0;
        if (pad) v = (v + 15) & ~15;
        int incl = v;
        #pragma unroll
        for (int d = 1; d < 64; d <<= 1) {
            int t = __shfl_up(incl, d);
            if (lane >= d) incl += t;
        }
        if (lane == 63) s_wtot[wid] = incl;
        __syncthreads();
        if (tid < 4) {
            int t = s_wtot[tid];
            int s = t;
            #pragma unroll
            for (int d = 1; d < 4; d <<= 1) {
                int x = __shfl_up(s, d);
                if (tid >= d) s += x;
            }
            s_woff[tid] = s - t;
            if (tid == 3) s_tot = s;
        }
        __syncthreads();
        int excl = incl - v + s_woff[wid] + s_carry;
        if (i < n) { o[i] = excl; if (u) u[i] = excl; }
        __syncthreads();
        if (tid == 0) s_carry += s_tot;
        __syncthreads();
    }
    if (tid == 0) o[n] = s_carry;
    __syncthreads();
}

// ======================= stage1: per-tile hist -> M rows | gg hist+scan | prep =======================

__global__ __launch_bounds__(256) void stage1_kernel(
    const int* __restrict__ dst_cg, int e_cg, int* __restrict__ M_cg, int nt_cg,
    const int* __restrict__ dst_gc, int e_gc, int* __restrict__ M_gc, int nt_gc,
    const int* __restrict__ dst_gg, int e_gg, int* __restrict__ cnt_gg,
    int* __restrict__ off_gg, int* __restrict__ cur_gg, int* __restrict__ done_gg,
    const float* __restrict__ cj_cell, const float* __restrict__ mask_exp,
    const float* __restrict__ cj_gene, const float* __restrict__ mask_rev,
    const float* __restrict__ cjj_gene, const float* __restrict__ mask_gg,
    float* __restrict__ w_cell, float* __restrict__ w_rev, float* __restrict__ w_gg,
    const float* __restrict__ c_feat, const float* __restrict__ g_feat,
    unsigned short* __restrict__ cf16, unsigned short* __restrict__ gf16, int do_cvt)
{
    const int tid = threadIdx.x;
    const int NT2 = nt_cg + nt_gc;

    if (blockIdx.x >= NT2 + 64) {              // ---- prep blocks ----
        const int pb = blockIdx.x - NT2 - 64;
        const long long stride = (long long)NPREP * 256;
        for (long long i = (long long)pb * 256 + tid; i < NC; i += stride)
            w_cell[i] = cj_cell[i] * mask_exp[i];
        for (long long i = (long long)pb * 256 + tid; i < NG; i += stride) {
            w_rev[i] = cj_gene[i] * mask_rev[i];
            w_gg[i]  = cjj_gene[i] * mask_gg[i];
        }
        if (do_cvt) {
            const long long total8 = (long long)(NC + NG) * D / 8;
            for (long long t = (long long)pb * 256 + tid; t < total8; t += stride) {
                const long long base = t * 8;
                const float* sp; unsigned short* dp;
                if (base < (long long)NC * D) { sp = c_feat + base; dp = cf16 + base; }
                else { sp = g_feat + (base - (long long)NC * D); dp = gf16 + (base - (long long)NC * D); }
                const float4 a = ((const float4*)sp)[0];
                const float4 b = ((const float4*)sp)[1];
                ((ushort4*)dp)[0] = make_ushort4(f2bf(a.x), f2bf(a.y), f2bf(a.z), f2bf(a.w));
                ((ushort4*)dp)[1] = make_ushort4(f2bf(b.x), f2bf(b.y), f2bf(b.z), f2bf(b.w));
            }
        }
        return;
    }

    __shared__ int h[NG];                      // 12 KB, reused by both branches

    if (blockIdx.x >= NT2) {                   // ---- gg hist (64 blocks) + last-block scan ----
        const int bid = blockIdx.x - NT2;
        for (int i = tid; i < NG; i += 256) h[i] = 0;
        __syncthreads();
        for (long long e = (long long)bid * 256 + tid; e < e_gg; e += (long long)64 * 256) {
            const int d = dst_gg[e];
            if (d >= 0 && d < NG) atomicAdd(&h[d], 1);
        }
        __syncthreads();
        for (int i = tid; i < NG; i += 256) {
            int v = h[i];
            if (v) atomicAdd(&cnt_gg[i], v);
        }
        __threadfence();
        __shared__ int lastflag;
        if (tid == 0) lastflag = (atomicAdd(done_gg, 1) == 63) ? 1 : 0;
        __syncthreads();
        if (!lastflag) return;
        __threadfence();
        block_scan256(cnt_gg, off_gg, cur_gg, NG, 0);
        return;
    }

    // ---- per-tile bin histogram -> M[t] row ----
    const int* dst; int ne, nbins, shift, t; int* M;
    if (blockIdx.x < nt_cg) { dst = dst_cg; ne = e_cg; nbins = NB_CG; shift = 2; t = blockIdx.x;         M = M_cg; }
    else                    { dst = dst_gc; ne = e_gc; nbins = NB_GC; shift = 6; t = blockIdx.x - nt_cg; M = M_gc; }
    const long long tb = (long long)t * TILE;
    if (tb >= ne) return;
    const int n = (int)((ne - tb) < TILE ? (ne - tb) : TILE);

    for (int i = tid; i < nbins; i += 256) h[i] = 0;
    __syncthreads();
    #pragma unroll 4
    for (int k = 0; k < TILE / 256; ++k) {
        int i = k * 256 + tid;
        if (i < n) {
            unsigned b = ((unsigned)dst[tb + i]) >> shift;
            if (b < (unsigned)nbins) atomicAdd(&h[b], 1);
        }
    }
    __syncthreads();
    for (int i = tid; i < nbins; i += 256)
        M[(size_t)t * nbins + i] = h[i];
}

// ======================= scan2: per-bin prefix over tiles (in place) + totals + bin offsets =======================

__global__ __launch_bounds__(256) void scan2_kernel(
    int* __restrict__ M_cg, int nt_cg, int* __restrict__ cnt_cg, int* __restrict__ off_cg,
    int* __restrict__ M_gc, int nt_gc, int* __restrict__ cnt_gc, int* __restrict__ off_gc,
    int* __restrict__ done)
{
    int nbins, nt, b; int* M; int* cnt;
    if (blockIdx.x < 3) { nbins = NB_CG; nt = nt_cg; M = M_cg; cnt = cnt_cg; b = blockIdx.x * 256 + threadIdx.x; }
    else                { nbins = NB_GC; nt = nt_gc; M = M_gc; cnt = cnt_gc; b = (blockIdx.x - 3) * 256 + threadIdx.x; }

    if (b < nbins) {
        int carry = 0;
        int t = 0;
        for (; t + 4 <= nt; t += 4) {
            size_t i0 = (size_t)t * nbins + b;
            int v0 = M[i0];
            int v1 = M[i0 + (size_t)nbins];
            int v2 = M[i0 + (size_t)2 * nbins];
            int v3 = M[i0 + (size_t)3 * nbins];
            M[i0] = carry;                       carry += v0;
            M[i0 + (size_t)nbins] = carry;       carry += v1;
            M[i0 + (size_t)2 * nbins] = carry;   carry += v2;
            M[i0 + (size_t)3 * nbins] = carry;   carry += v3;
        }
        for (; t < nt; ++t) {
            size_t i = (size_t)t * nbins + b;
            int v = M[i]; M[i] = carry; carry += v;
        }
        M[(size_t)nt * nbins + b] = carry;       // totals row
        cnt[b] = carry;
    }

    __threadfence();
    __shared__ int lastflag;
    if (threadIdx.x == 0) lastflag = (atomicAdd(done, 1) == NSCAN2 - 1) ? 1 : 0;
    __syncthreads();
    if (!lastflag) return;
    __threadfence();
    block_scan256(cnt_cg, off_cg, nullptr, NB_CG, 1);
    block_scan256(cnt_gc, off_gc, nullptr, NB_GC, 1);
}

// ======================= part3: atomic-free tile partition + gg fill =======================

__global__ __launch_bounds__(256) void part3_kernel(
    const int* __restrict__ src_cg, const int* __restrict__ dst_cg, int e_cg,
    const int* __restrict__ M_cg, const int* __restrict__ off_cg,
    unsigned* __restrict__ ubkt_cg, int cap_cg, int nt_cg,
    const int* __restrict__ src_gc, const int* __restrict__ dst_gc, int e_gc,
    const int* __restrict__ M_gc, const int* __restrict__ off_gc,
    unsigned* __restrict__ ubkt_gc, int cap_gc, int nt_gc,
    const int* __restrict__ src_gg, const int* __restrict__ dst_gg, int e_gg,
    int* __restrict__ cur_gg, int* __restrict__ bkt_gg)
{
    const int tid = threadIdx.x;
    if (blockIdx.x >= nt_cg + nt_gc) {   // gg fill (64 blocks)
        for (long long e = (long long)(blockIdx.x - nt_cg - nt_gc) * 256 + tid; e < e_gg;
             e += (long long)64 * 256) {
            int pos = atomicAdd(&cur_gg[dst_gg[e]], 1);
            if (pos >= 0 && pos < e_gg) bkt_gg[pos] = src_gg[e];
        }
        return;
    }
    const int* src; const int* dst; int ne; const int* M; const int* off;
    unsigned* bkt; int cap, shift, nbins, t;
    if (blockIdx.x < nt_cg) { src = src_cg; dst = dst_cg; ne = e_cg; M = M_cg; off = off_cg; bkt = ubkt_cg; cap = cap_cg; shift = 2; nbins = NB_CG; t = blockIdx.x; }
    else                    { src = src_gc; dst = dst_gc; ne = e_gc; M = M_gc; off = off_gc; bkt = ubkt_gc; cap = cap_gc; shift = 6; nbins = NB_GC; t = blockIdx.x - nt_cg; }
    const long long tb = (long long)t * TILE;
    if (tb >= ne) return;
    const int n = (int)((ne - tb) < TILE ? (ne - tb) : TILE);

    __shared__ int th[784];
    __shared__ int toff[784];
    __shared__ int tcur[784];
    __shared__ int gs[784];
    __shared__ unsigned staged[TILE];
    const unsigned PMASK = (1u << PBITS) - 1u;
    const unsigned DMASK = (1u << shift) - 1u;

    // load deterministic run starts + per-tile counts (no hist, no global atomics)
    for (int i = tid; i < nbins; i += 256) {
        size_t r0 = (size_t)t * nbins + i;
        int m0 = M[r0];
        int m1 = M[r0 + (size_t)nbins];
        gs[i] = off[i] + m0;
        th[i] = m1 - m0;
        tcur[i] = 0;
    }
    __syncthreads();
    if (tid < 64) {                      // local exclusive scan th -> toff
        int carry = 0;
        for (int c = 0; c < nbins; c += 64) {
            int idx = c + tid;
            int v = (idx < nbins) ? th[idx] : 0;
            int incl = v;
            #pragma unroll
            for (int d = 1; d < 64; d <<= 1) {
                int x = __shfl_up(incl, d);
                if (tid >= d) incl += x;
            }
            if (idx < nbins) toff[idx] = incl - v + carry;
            carry += __shfl(incl, 63);
        }
    }
    __syncthreads();
    #pragma unroll 4
    for (int k = 0; k < TILE / 256; ++k) {   // place (bin-sorted into LDS)
        int i = k * 256 + tid;
        if (i < n) {
            unsigned d = (unsigned)dst[tb + i];
            unsigned s = (unsigned)src[tb + i];
            unsigned b = d >> shift;
            if (b < (unsigned)nbins) {
                int p = toff[b] + atomicAdd(&tcur[b], 1);
                if (p >= 0 && p < TILE)
                    staged[p] = (b << PBITS) | (s << shift) | (d & DMASK);
            }
        }
    }
    __syncthreads();
    for (int i = tid; i < n; i += 256) {     // flush contiguous runs
        unsigned v = staged[i];
        unsigned b = v >> PBITS;
        long long g = (long long)gs[b] + (i - toff[b]);
        if (g >= 0 && g < cap) bkt[g] = v & PMASK;
    }
}

// ======================= fused gather (cg + gg fold | gc), src-tile-sorted =======================

template <bool BF16>
__global__ __launch_bounds__(256) void gather3_kernel(
    const unsigned* __restrict__ ubkt_cg, const int* __restrict__ cntb_cg, const int* __restrict__ offb_cg,
    const unsigned* __restrict__ ubkt_gc, const int* __restrict__ cntb_gc, const int* __restrict__ offb_gc,
    const void* __restrict__ cfeat, const void* __restrict__ gfeat,
    const float* __restrict__ w_cell, const float* __restrict__ w_rev, const float* __restrict__ w_gg,
    const float* __restrict__ ci_gene, const float* __restrict__ cii_gene, const float* __restrict__ ci_cell,
    const int* __restrict__ off_gg, const int* __restrict__ bkt_gg, int e_gg,
    float* __restrict__ g_out, float* __restrict__ c_out)
{
    __shared__ unsigned sorted[CAPV];
    __shared__ int lh[64];
    __shared__ int loff[64];
    __shared__ int lcur[64];

    const bool is_cg = (blockIdx.x < NB_CG);
    const int bin = is_cg ? blockIdx.x : blockIdx.x - NB_CG;
    const int n = (is_cg ? cntb_cg : cntb_gc)[bin];
    const long long base = (is_cg ? offb_cg : offb_gc)[bin];
    const unsigned* bkt = is_cg ? ubkt_cg : ubkt_gc;
    const void* feat = is_cg ? cfeat : gfeat;
    const float* wsrc = is_cg ? w_cell : w_rev;
    const int shift = is_cg ? 2 : 6;
    const int DIVv = is_cg ? 4 : 64;
    const int KPC  = is_cg ? 16 : 1;     // sort keys per cell
    const int tid  = threadIdx.x;
    const int lane = tid & 63;
    const int wid  = tid >> 6;
    const int grp8 = lane >> 3;          // 8 groups of 8 lanes -> 8 edges in flight
    const int l8   = lane & 7;
    const bool fast = (n <= CAPV);

    if (fast) {
        for (int i = tid; i < 64; i += 256) { lh[i] = 0; lcur[i] = 0; }
        __syncthreads();
        for (int i = tid; i < n; i += 256) {
            const unsigned v = bkt[base + i];
            const int k = is_cg ? (int)(((v & 3u) << 4) | (((v >> 2) & 0xFFFFu) >> 12))
                                : (int)(v & 63u);
            atomicAdd(&lh[k], 1);
        }
        __syncthreads();
        if (tid < 64) {
            int v = lh[tid];
            int incl = v;
            #pragma unroll
            for (int d = 1; d < 64; d <<= 1) {
                int t = __shfl_up(incl, d);
                if (tid >= d) incl += t;
            }
            loff[tid] = incl - v;
        }
        __syncthreads();
        for (int i = tid; i < n; i += 256) {
            const unsigned v = bkt[base + i];
            const int k = is_cg ? (int)(((v & 3u) << 4) | (((v >> 2) & 0xFFFFu) >> 12))
                                : (int)(v & 63u);
            int p = loff[k] + atomicAdd(&lcur[k], 1);
            if (p >= 0 && p < CAPV) sorted[p] = v;
        }
        __syncthreads();
    }

    for (int cell = wid; cell < DIVv; cell += 4) {
        const int r = (bin << shift) + cell;
        if (r >= (is_cg ? NG : NC)) continue;

        float fA[8] = {0.f, 0.f, 0.f, 0.f, 0.f, 0.f, 0.f, 0.f};
        if (fast) {
            const int k0 = cell * KPC, k1 = k0 + KPC - 1;
            const int lo = loff[k0], hi = loff[k1] + lh[k1];
            for (int jj = lo; jj < hi; jj += 8) {
                const int j = jj + grp8;
                const bool valid = (j < hi);
                const unsigned v = valid ? sorted[j] : 0u;
                const int s = (v >> shift) & 0xFFFF;
                const float w = valid ? wsrc[s] : 0.0f;
                float f[8]; row8<BF16>(feat, s, l8, f);
                #pragma unroll
                for (int q = 0; q < 8; ++q) fA[q] += w * f[q];
            }
        } else {
            for (int jj = 0; jj < n; jj += 8) {
                const int j = jj + grp8;
                const bool valid = (j < n);
                const unsigned v = valid ? bkt[base + j] : 0u;
                const bool ok = valid && ((int)(v & (unsigned)(DIVv - 1)) == cell);
                const int s = (v >> shift) & 0xFFFF;
                const float w = ok ? wsrc[s] : 0.0f;
                float f[8]; row8<BF16>(feat, s, l8, f);
                #pragma unroll
                for (int q = 0; q < 8; ++q) fA[q] += w * f[q];
            }
        }

        float fB[8] = {0.f, 0.f, 0.f, 0.f, 0.f, 0.f, 0.f, 0.f};
        if (is_cg) {
            int lo2 = off_gg[r], hi2 = off_gg[r + 1];
            lo2 = lo2 < 0 ? 0 : (lo2 > e_gg ? e_gg : lo2);
            hi2 = hi2 < 0 ? 0 : (hi2 > e_gg ? e_gg : hi2);
            for (int jj = lo2; jj < hi2; jj += 8) {
                const int j = jj + grp8;
                const bool valid = (j < hi2);
                const int s = valid ? bkt_gg[j] : 0;
                const float w = valid ? w_gg[s] : 0.0f;
                float f[8]; row8<BF16>(gfeat, s, l8, f);
                #pragma unroll
                for (int q = 0; q < 8; ++q) fB[q] += w * f[q];
            }
        }

        #pragma unroll
        for (int q = 0; q < 8; ++q) {
            #pragma unroll
            for (int off = 8; off < 64; off <<= 1) fA[q] += __shfl_xor(fA[q], off);
        }
        if (is_cg) {
            #pragma unroll
            for (int q = 0; q < 8; ++q) {
                #pragma unroll
                for (int off = 8; off < 64; off <<= 1) fB[q] += __shfl_xor(fB[q], off);
            }
        }

        if (grp8 == 0) {
            float o[8];
            float* outp;
            if (is_cg) {
                const float sa = 0.5f * ci_gene[r];
                const float sb = 0.5f * cii_gene[r];
                outp = g_out + (size_t)r * D;
                #pragma unroll
                for (int q = 0; q < 8; ++q) o[q] = sa * fA[q] + sb * fB[q];
            } else {
                const float sc = ci_cell[r];
                outp = c_out + (size_t)r * D;
                #pragma unroll
                for (int q = 0; q < 8; ++q) o[q] = sc * fA[q];
            }
            if (BF16) {
                *(float4*)(outp + 8 * l8)     = make_float4(o[0], o[1], o[2], o[3]);
                *(float4*)(outp + 8 * l8 + 4) = make_float4(o[4], o[5], o[6], o[7]);
            } else {
                *(float4*)(outp + 4 * l8)      = make_float4(o[0], o[1], o[2], o[3]);
                *(float4*)(outp + 32 + 4 * l8) = make_float4(o[4], o[5], o[6], o[7]);
            }
        }
    }
}

// ======================= fallback (atomic scatter) =======================

__global__ __launch_bounds__(256) void edge_scatter_kernel(
    const float* __restrict__ feat, const float* __restrict__ cj,
    const float* __restrict__ mask, const float* __restrict__ ci,
    const int* __restrict__ src, const int* __restrict__ dst,
    float* __restrict__ out, int nedges, float alpha)
{
    const int lane16 = threadIdx.x & 15;
    const int eloc   = threadIdx.x >> 4;
    const long long e = (long long)blockIdx.x * 16 + eloc;
    if (e >= nedges) return;
    const int s = src[e];
    const int t = dst[e];
    const float w = cj[s] * mask[s] * ci[t] * alpha;
    const float4 v = *(const float4*)(feat + (size_t)s * D + lane16 * 4);
    float* o = out + (size_t)t * D + lane16 * 4;
#if defined(__HIP_DEVICE_COMPILE__)
    unsafeAtomicAdd(o + 0, w * v.x);
    unsafeAtomicAdd(o + 1, w * v.y);
    unsafeAtomicAdd(o + 2, w * v.z);
    unsafeAtomicAdd(o + 3, w * v.w);
#endif
}

// ======================= launch =======================

extern "C" void kernel_launch(void* const* d_in, const int* in_sizes, int n_in,
                              void* d_out, int out_size, void* d_ws, size_t ws_size,
                              hipStream_t stream)
{
    const float* c_feat   = (const float*)d_in[0];
    const float* g_feat   = (const float*)d_in[1];
    const float* cj_cell  = (const float*)d_in[2];
    const float* ci_cell  = (const float*)d_in[3];
    const float* cj_gene  = (const float*)d_in[4];
    const float* ci_gene  = (const float*)d_in[5];
    const float* cjj_gene = (const float*)d_in[6];
    const float* cii_gene = (const float*)d_in[7];
    const float* mask_exp = (const float*)d_in[8];
    const float* mask_rev = (const float*)d_in[9];
    const float* mask_gg  = (const float*)d_in[10];
    const int*   src_cg   = (const int*)d_in[11];
    const int*   dst_cg   = (const int*)d_in[12];
    const int*   src_gc   = (const int*)d_in[13];
    const int*   dst_gc   = (const int*)d_in[14];
    const int*   src_gg   = (const int*)d_in[15];
    const int*   dst_gg   = (const int*)d_in[16];

    const int e_cg = in_sizes[11];
    const int e_gc = in_sizes[13];
    const int e_gg = in_sizes[15];

    float* c_out = (float*)d_out;                   // [NC, D]
    float* g_out = (float*)d_out + (size_t)NC * D;  // [NG, D]

    const int cap_cg = e_cg + 16 * NB_CG;
    const int cap_gc = e_gc + 16 * NB_GC;
    const int nt_cg = (e_cg + TILE - 1) / TILE;
    const int nt_gc = (e_gc + TILE - 1) / TILE;

    // ---- workspace layout (int units) ----
    int* ws = (int*)d_ws;
    size_t p = 0;
    int* cnt_gg  = ws + p; p += NG;        // memset region start
    int* done_gg = ws + p; p += 1;
    int* done_s2 = ws + p; p += 1;         // memset region end (NG + 2 ints)
    int* cnt_cg  = ws + p; p += NB_CG;
    int* cnt_gc  = ws + p; p += NB_GC;
    int* off_cg  = ws + p; p += NB_CG + 1;
    int* off_gc  = ws + p; p += NB_GC + 1;
    int* off_gg  = ws + p; p += NG + 1;
    int* cur_gg  = ws + p; p += NG;
    float* w_cell = (float*)(ws + p); p += NC;
    float* w_rev  = (float*)(ws + p); p += NG;
    float* w_gg   = (float*)(ws + p); p += NG;
    int* M_cg = ws + p; p += (size_t)(nt_cg + 1) * NB_CG;
    int* M_gc = ws + p; p += (size_t)(nt_gc + 1) * NB_GC;
    unsigned* ubkt_cg = (unsigned*)(ws + p); p += cap_cg;
    unsigned* ubkt_gc = (unsigned*)(ws + p); p += cap_gc;
    int* bkt_gg = ws + p; p += e_gg;
    const size_t need_base = p * sizeof(int);
    unsigned short* cf16 = (unsigned short*)(ws + p); p += (size_t)NC * D / 2;
    unsigned short* gf16 = (unsigned short*)(ws + p); p += (size_t)NG * D / 2;
    const size_t need_full = p * sizeof(int);

    if (need_base > ws_size) {
        hipMemsetAsync(d_out, 0, (size_t)out_size * sizeof(float), stream);
        edge_scatter_kernel<<<(e_cg + 15) / 16, 256, 0, stream>>>(
            c_feat, cj_cell, mask_exp, ci_gene, src_cg, dst_cg, g_out, e_cg, 0.5f);
        edge_scatter_kernel<<<(e_gc + 15) / 16, 256, 0, stream>>>(
            g_feat, cj_gene, mask_rev, ci_cell, src_gc, dst_gc, c_out, e_gc, 1.0f);
        edge_scatter_kernel<<<(e_gg + 15) / 16, 256, 0, stream>>>(
            g_feat, cjj_gene, mask_gg, cii_gene, src_gg, dst_gg, g_out, e_gg, 0.5f);
        return;
    }
    const int use_bf16 = (need_full <= ws_size) ? 1 : 0;

    hipMemsetAsync(cnt_gg, 0, (size_t)(NG + 2) * sizeof(int), stream);

    stage1_kernel<<<nt_cg + nt_gc + 64 + NPREP, 256, 0, stream>>>(
        dst_cg, e_cg, M_cg, nt_cg,
        dst_gc, e_gc, M_gc, nt_gc,
        dst_gg, e_gg, cnt_gg, off_gg, cur_gg, done_gg,
        cj_cell, mask_exp, cj_gene, mask_rev, cjj_gene, mask_gg,
        w_cell, w_rev, w_gg, c_feat, g_feat, cf16, gf16, use_bf16);

    scan2_kernel<<<NSCAN2, 256, 0, stream>>>(
        M_cg, nt_cg, cnt_cg, off_cg,
        M_gc, nt_gc, cnt_gc, off_gc, done_s2);

    part3_kernel<<<nt_cg + nt_gc + 64, 256, 0, stream>>>(
        src_cg, dst_cg, e_cg, M_cg, off_cg, ubkt_cg, cap_cg, nt_cg,
        src_gc, dst_gc, e_gc, M_gc, off_gc, ubkt_gc, cap_gc, nt_gc,
        src_gg, dst_gg, e_gg, cur_gg, bkt_gg);

    if (use_bf16) {
        gather3_kernel<true><<<NB_CG + NB_GC, 256, 0, stream>>>(
            ubkt_cg, cnt_cg, off_cg, ubkt_gc, cnt_gc, off_gc,
            (const void*)cf16, (const void*)gf16,
            w_cell, w_rev, w_gg, ci_gene, cii_gene, ci_cell,
            off_gg, bkt_gg, e_gg, g_out, c_out);
    } else {
        gather3_kernel<false><<<NB_CG + NB_GC, 256, 0, stream>>>(
            ubkt_cg, cnt_cg, off_cg, ubkt_gc, cnt_gc, off_gc,
            (const void*)c_feat, (const void*)g_feat,
            w_cell, w_rev, w_gg, ci_gene, cii_gene, ci_cell,
            off_gg, bkt_gg, e_gg, g_out, c_out);
    }
}